// Round 13
// baseline (2166.655 us; speedup 1.0000x reference)
//
#include <hip/hip_runtime.h>

typedef unsigned short u16;
typedef __attribute__((ext_vector_type(4))) float f32x4;
typedef __attribute__((ext_vector_type(8))) short s16x8;

#define NND 50000      // nodes per side (NU == NI)
#define EDG 1600000    // edges per relation
#define NBK 391        // buckets per relation = ceil(NND/128)
#define TOTB (3 * NBK)
#define TS 4096        // edges per scatter tile
#define CAPB 5120      // fixed bucket capacity (mean 4092, sd 64 -> +16 sigma)
#define GEMMB (NBK * 4)   // 1564 gemm blocks
#define QKB 1536
#define EDGEB (NND / 2)   // 25000 edge blocks

__device__ __forceinline__ u16 f2b(float f) {
  union { float f; unsigned u; } c; c.f = f;
  unsigned r = c.u + 0x7fff + ((c.u >> 16) & 1);   // RNE
  return (u16)(r >> 16);
}

__device__ __forceinline__ void accum8(float* num, uint4 u, float4 w0, float4 w1) {
  num[0] += w0.x * __int_as_float((int)(u.x << 16));
  num[1] += w0.y * __int_as_float((int)(u.x & 0xFFFF0000u));
  num[2] += w0.z * __int_as_float((int)(u.y << 16));
  num[3] += w0.w * __int_as_float((int)(u.y & 0xFFFF0000u));
  num[4] += w1.x * __int_as_float((int)(u.z << 16));
  num[5] += w1.y * __int_as_float((int)(u.z & 0xFFFF0000u));
  num[6] += w1.z * __int_as_float((int)(u.w << 16));
  num[7] += w1.w * __int_as_float((int)(u.w & 0xFFFF0000u));
}

struct EdgeSmem {
  float exw[4][512];
  int sarr[4][64];
  float sd[4][8];
  float sacc[4][64];
};
struct GemmSmem {
  u16 sA[128 * 72];
  u16 sB[128 * 72];
};
union Smem { EdgeSmem e; GemmSmem g; };

// ================= bodies =================
__device__ void gemm_body(GemmSmem& sm, const float* __restrict__ A, const u16* __restrict__ Bt,
                          const float* __restrict__ bias, u16* __restrict__ C, int bx) {
  int tid = threadIdx.x;
  int lane = tid & 63, wid = tid >> 6;
  int wm = wid >> 1, wn = wid & 1;
  int l15 = lane & 15, l4 = lane >> 4;
  int m0 = (bx >> 2) * 128, n0 = (bx & 3) * 128;
  f32x4 acc[4][4] = {};
  for (int ko = 0; ko < 256; ko += 64) {
#pragma unroll
    for (int p = 0; p < 4; p++) {
      int idx = p * 256 + tid;
      int row = idx >> 3, seg = idx & 7;
      int gm = m0 + row; if (gm >= NND) gm = NND - 1;
      float4 a0 = *(const float4*)(A + (size_t)gm * 256 + ko + seg * 8);
      float4 a1 = *(const float4*)(A + (size_t)gm * 256 + ko + seg * 8 + 4);
      s16x8 av;
      av[0] = (short)f2b(a0.x); av[1] = (short)f2b(a0.y);
      av[2] = (short)f2b(a0.z); av[3] = (short)f2b(a0.w);
      av[4] = (short)f2b(a1.x); av[5] = (short)f2b(a1.y);
      av[6] = (short)f2b(a1.z); av[7] = (short)f2b(a1.w);
      *(s16x8*)&sm.sA[row * 72 + seg * 8] = av;
      *(s16x8*)&sm.sB[row * 72 + seg * 8] = *(const s16x8*)(Bt + (size_t)(n0 + row) * 256 + ko + seg * 8);
    }
    __syncthreads();
#pragma unroll
    for (int kk = 0; kk < 2; kk++) {
      s16x8 af[4], bf[4];
#pragma unroll
      for (int i = 0; i < 4; i++) af[i] = *(const s16x8*)&sm.sA[(wm * 64 + i * 16 + l15) * 72 + kk * 32 + l4 * 8];
#pragma unroll
      for (int j = 0; j < 4; j++) bf[j] = *(const s16x8*)&sm.sB[(wn * 64 + j * 16 + l15) * 72 + kk * 32 + l4 * 8];
#pragma unroll
      for (int i = 0; i < 4; i++)
#pragma unroll
        for (int j = 0; j < 4; j++)
          acc[i][j] = __builtin_amdgcn_mfma_f32_16x16x32_bf16(af[i], bf[j], acc[i][j], 0, 0, 0);
    }
    __syncthreads();
  }
#pragma unroll
  for (int j = 0; j < 4; j++) {
    int n = n0 + wn * 64 + j * 16 + l15;
    float bb = bias[n];
    int tpos = ((n & 63) << 3) + (n >> 6);          // head-transposed column
#pragma unroll
    for (int i = 0; i < 4; i++) {
      int mb = m0 + wm * 64 + i * 16 + l4 * 4;
#pragma unroll
      for (int r = 0; r < 4; r++) {
        int m = mb + r;
        if (m < NND) C[(size_t)m * 512 + tpos] = f2b(acc[i][j][r] + bb);
      }
    }
  }
}

__device__ void edge_body(EdgeSmem& sm, int bx,
                          const int* __restrict__ rp, const int* __restrict__ dg,
                          const u16* __restrict__ csrc, const float* __restrict__ q,
                          const float* __restrict__ k, const u16* __restrict__ hs,
                          float* __restrict__ out, float scale, int accum) {
  int lane = threadIdx.x & 63, w = threadIdx.x >> 6;
  int dst = bx * 2 + (w >> 1);
  int half = w & 1;
  int beg = rp[dst];
  int deg = dg[dst];
  int hlen = (deg + 1) >> 1;
  int s0 = half ? hlen : 0;
  int s1 = half ? deg : hlen;
  float qv[8];
  {
    float4 q0 = *(const float4*)(q + dst * 8);
    float4 q1 = *(const float4*)(q + dst * 8 + 4);
    qv[0] = q0.x; qv[1] = q0.y; qv[2] = q0.z; qv[3] = q0.w;
    qv[4] = q1.x; qv[5] = q1.y; qv[6] = q1.z; qv[7] = q1.w;
  }
  float num[8] = {0, 0, 0, 0, 0, 0, 0, 0};
  float dsum[8] = {0, 0, 0, 0, 0, 0, 0, 0};
  for (int base = s0; base < s1; base += 64) {
    int i = base + lane;
    int nn = min(64, s1 - base);
    if (i < s1) {
      int s = (int)csrc[beg + i];
      sm.sarr[w][lane] = s;
      float4 k0 = *(const float4*)(k + s * 8);
      float4 k1 = *(const float4*)(k + s * 8 + 4);
      float kv[8] = {k0.x, k0.y, k0.z, k0.w, k1.x, k1.y, k1.z, k1.w};
#pragma unroll
      for (int h = 0; h < 8; h++) {
        float e = qv[h] + kv[h];
        e = e > 0.f ? e : 0.2f * e;
        float wgt = exp2f(e * 1.44269504f);
        sm.exw[w][lane * 8 + h] = wgt;
        dsum[h] += wgt;
      }
    }
    __asm__ __volatile__("s_waitcnt lgkmcnt(0)" ::: "memory");
    int j = 0;
    for (; j + 4 <= nn; j += 4) {
      int sa = sm.sarr[w][j], sb = sm.sarr[w][j + 1], sc = sm.sarr[w][j + 2], sdn = sm.sarr[w][j + 3];
      uint4 ua = *(const uint4*)(hs + (size_t)sa * 512 + lane * 8);
      uint4 ub = *(const uint4*)(hs + (size_t)sb * 512 + lane * 8);
      uint4 uc = *(const uint4*)(hs + (size_t)sc * 512 + lane * 8);
      uint4 ud = *(const uint4*)(hs + (size_t)sdn * 512 + lane * 8);
      float4 wa0 = *(const float4*)&sm.exw[w][j * 8],       wa1 = *(const float4*)&sm.exw[w][j * 8 + 4];
      float4 wb0 = *(const float4*)&sm.exw[w][j * 8 + 8],   wb1 = *(const float4*)&sm.exw[w][j * 8 + 12];
      float4 wc0 = *(const float4*)&sm.exw[w][j * 8 + 16],  wc1 = *(const float4*)&sm.exw[w][j * 8 + 20];
      float4 wd0 = *(const float4*)&sm.exw[w][j * 8 + 24],  wd1 = *(const float4*)&sm.exw[w][j * 8 + 28];
      accum8(num, ua, wa0, wa1);
      accum8(num, ub, wb0, wb1);
      accum8(num, uc, wc0, wc1);
      accum8(num, ud, wd0, wd1);
    }
    for (; j < nn; j++) {
      int s = sm.sarr[w][j];
      uint4 u = *(const uint4*)(hs + (size_t)s * 512 + lane * 8);
      float4 e0 = *(const float4*)&sm.exw[w][j * 8];
      float4 e1 = *(const float4*)&sm.exw[w][j * 8 + 4];
      accum8(num, u, e0, e1);
    }
  }
#pragma unroll
  for (int off = 1; off < 64; off <<= 1)
#pragma unroll
    for (int h = 0; h < 8; h++) dsum[h] += __shfl_xor(dsum[h], off, 64);
  if (lane == 0) {
#pragma unroll
    for (int h = 0; h < 8; h++) sm.sd[w][h] = dsum[h];
  }
  __syncthreads();
  float acc = 0.f;
#pragma unroll
  for (int h = 0; h < 8; h++) {
    float tot = sm.sd[w][h] + sm.sd[w ^ 1][h];
    float rden = tot > 0.f ? 1.f / tot : 0.f;
    acc += num[h] * rden;
  }
  acc *= scale;
  sm.sacc[w][lane] = acc;
  __syncthreads();
  if (half == 0) {
    float tot = sm.sacc[w][lane] + sm.sacc[w + 1][lane];
    if (accum) out[dst * 64 + lane] += tot;
    else out[dst * 64 + lane] = tot;
  }
}

__device__ void qk_body(int qb, const float* __restrict__ xu, const float* __restrict__ xi,
                        const float* __restrict__ FW, const float* __restrict__ FB,
                        float* __restrict__ K0, float* __restrict__ Q1, float* __restrict__ Q2,
                        float* __restrict__ K2, float* __restrict__ Q0, float* __restrict__ K1) {
  int lane = threadIdx.x & 63, wid = threadIdx.x >> 6;
  if (qb < 1024) {
    int stride = 1024 * 4;
    for (int row = qb * 4 + wid; row < NND; row += stride) {
      float4 xv = *(const float4*)(xu + (size_t)row * 256 + lane * 4);
      {
        float p[16];
#pragma unroll
        for (int c = 0; c < 16; c++) {
          const float4 wv = *(const float4*)(FW + (size_t)(8 + c) * 256 + lane * 4);
          p[c] = xv.x * wv.x + xv.y * wv.y + xv.z * wv.z + xv.w * wv.w;
        }
#pragma unroll
        for (int off = 1; off < 64; off <<= 1)
#pragma unroll
          for (int c = 0; c < 16; c++) p[c] += __shfl_xor(p[c], off, 64);
        if (lane == 0) {
#pragma unroll
          for (int c = 0; c < 8; c++) K0[row * 8 + c] = p[c] + FB[8 + c];
#pragma unroll
          for (int c = 0; c < 8; c++) Q1[row * 8 + c] = p[8 + c] + FB[16 + c];
        }
      }
      {
        float p[16];
#pragma unroll
        for (int c = 0; c < 16; c++) {
          const float4 wv = *(const float4*)(FW + (size_t)(32 + c) * 256 + lane * 4);
          p[c] = xv.x * wv.x + xv.y * wv.y + xv.z * wv.z + xv.w * wv.w;
        }
#pragma unroll
        for (int off = 1; off < 64; off <<= 1)
#pragma unroll
          for (int c = 0; c < 16; c++) p[c] += __shfl_xor(p[c], off, 64);
        if (lane == 0) {
#pragma unroll
          for (int c = 0; c < 8; c++) Q2[row * 8 + c] = p[c] + FB[32 + c];
#pragma unroll
          for (int c = 0; c < 8; c++) K2[row * 8 + c] = p[8 + c] + FB[40 + c];
        }
      }
    }
  } else {
    int b = qb - 1024;
    int stride = 512 * 4;
    for (int row = b * 4 + wid; row < NND; row += stride) {
      float4 xv = *(const float4*)(xi + (size_t)row * 256 + lane * 4);
      float p[16];
#pragma unroll
      for (int c = 0; c < 16; c++) {
        const float4 wv = *(const float4*)(FW + (size_t)((c < 8) ? c : (16 + c)) * 256 + lane * 4);
        p[c] = xv.x * wv.x + xv.y * wv.y + xv.z * wv.z + xv.w * wv.w;
      }
#pragma unroll
      for (int off = 1; off < 64; off <<= 1)
#pragma unroll
        for (int c = 0; c < 16; c++) p[c] += __shfl_xor(p[c], off, 64);
      if (lane == 0) {
#pragma unroll
        for (int c = 0; c < 8; c++) Q0[row * 8 + c] = p[c] + FB[c];
#pragma unroll
        for (int c = 0; c < 8; c++) K1[row * 8 + c] = p[8 + c] + FB[24 + c];
      }
    }
  }
}

// ================= kernels =================
__global__ void k_prepw(const float* __restrict__ Wv, u16* __restrict__ Wt,
                        float* __restrict__ Wvt, int* __restrict__ bcur) {
  int tid = blockIdx.x * 256 + threadIdx.x;
  if (tid < 3 * 512 * 256) {
    int r = tid / (512 * 256); int rem = tid - r * 512 * 256;
    int n = rem >> 8; int kk = rem & 255;
    float v = Wv[((size_t)r * 256 + kk) * 512 + n];
    Wt[tid] = f2b(v);
    Wvt[tid] = v;
  }
  if (tid < TOTB) bcur[tid] = tid * CAPB;
}

__global__ void __launch_bounds__(256) k_fusew2(
    const float* __restrict__ Wvt, const float* __restrict__ bv,
    const float* __restrict__ Wq, const float* __restrict__ bq,
    const float* __restrict__ Wk, const float* __restrict__ bk,
    float* __restrict__ FW, float* __restrict__ FB) {
  __shared__ float red[256];
  int r = blockIdx.x >> 4, o = blockIdx.x & 15;
  int t = threadIdx.x;
  const float* wvt = Wvt + (size_t)r * 512 * 256;
  const float* wqk = (o < 8) ? (Wq + (size_t)r * 512 * 8 + o) : (Wk + (size_t)r * 512 * 8 + (o - 8));
  float acc = 0.f;
#pragma unroll 8
  for (int j = 0; j < 512; j++) acc += wvt[(size_t)j * 256 + t] * wqk[j * 8];
  FW[((size_t)r * 16 + o) * 256 + t] = acc;
  float pb = 0.f;
  for (int j = t; j < 512; j += 256) pb += bv[r * 512 + j] * wqk[j * 8];
  red[t] = pb;
  __syncthreads();
  for (int off = 128; off > 0; off >>= 1) {
    if (t < off) red[t] += red[t + off];
    __syncthreads();
  }
  if (t == 0) {
    float b = (o < 8) ? bq[r * 8 + o] : bk[r * 8 + (o - 8)];
    FB[r * 16 + o] = red[0] + b;
  }
}

__global__ void __launch_bounds__(256) kb_scatter(
    const int* __restrict__ s1, const int* __restrict__ d1,
    const int* __restrict__ s2, const int* __restrict__ d2,
    const int* __restrict__ s3, const int* __restrict__ d3,
    int* __restrict__ BCUR, unsigned* __restrict__ pairs) {
  __shared__ int h[NBK];
  __shared__ int bbase[NBK];
  int tid = threadIdx.x;
  int r = blockIdx.y;
  const int* dp = (r == 0) ? d1 : (r == 1) ? d2 : d3;
  const int* sp = (r == 0) ? s1 : (r == 1) ? s2 : s3;
  int e0 = blockIdx.x * TS;
  int n = EDG - e0; if (n > TS) n = TS;
  for (int b = tid; b < NBK; b += 256) h[b] = 0;
  __syncthreads();
  int eb[16]; unsigned ev[16];
#pragma unroll
  for (int k = 0; k < 16; k++) {
    int i = k * 256 + tid;
    if (i < n) {
      int d = dp[e0 + i], ss = sp[e0 + i];
      eb[k] = d >> 7;
      ev[k] = ((unsigned)(d & 127) << 16) | (unsigned)ss;
      atomicAdd(&h[eb[k]], 1);
    } else eb[k] = -1;
  }
  __syncthreads();
  for (int b = tid; b < NBK; b += 256) {
    int c = h[b];
    bbase[b] = c ? atomicAdd(&BCUR[r * NBK + b], c) : 0;
  }
  __syncthreads();
  for (int b = tid; b < NBK; b += 256) h[b] = 0;   // reuse as local cursor
  __syncthreads();
#pragma unroll
  for (int k = 0; k < 16; k++) {
    if (eb[k] >= 0) {
      int off = atomicAdd(&h[eb[k]], 1);
      int pos = bbase[eb[k]] + off;
      int limit = (r * NBK + eb[k] + 1) * CAPB;
      if (pos < limit) pairs[pos] = ev[k];     // 16-sigma guard vs OOB
    }
  }
}

__global__ void __launch_bounds__(256) kb_build(
    const unsigned* __restrict__ pairs, const int* __restrict__ BCUR,
    int* __restrict__ rp, int* __restrict__ dgarr, u16* __restrict__ csrc) {
  __shared__ int cntl[128];
  __shared__ int sc[128];
  __shared__ int curl[128];
  int t = threadIdx.x;
  int r = blockIdx.y, bx = blockIdx.x;
  int bin = r * NBK + bx;
  int base = bin * CAPB;
  int cnt = BCUR[bin] - base; if (cnt > CAPB) cnt = CAPB;
  int node0 = bx << 7;
  int nloc = NND - node0; if (nloc > 128) nloc = 128;
  if (t < 128) cntl[t] = 0;
  __syncthreads();
  for (int i = t; i < cnt; i += 256)
    atomicAdd(&cntl[pairs[base + i] >> 16], 1);
  __syncthreads();
  if (t < 128) sc[t] = cntl[t];
  __syncthreads();
  for (int off = 1; off < 128; off <<= 1) {
    int v = 0;
    if (t < 128) { v = sc[t]; if (t >= off) v += sc[t - off]; }
    __syncthreads();
    if (t < 128) sc[t] = v;
    __syncthreads();
  }
  if (t < 128) {
    int excl = sc[t] - cntl[t];
    if (t < nloc) { rp[r * NND + node0 + t] = base + excl; dgarr[r * NND + node0 + t] = cntl[t]; }
    curl[t] = base + excl;
  }
  __syncthreads();
  for (int i = t; i < cnt; i += 256) {
    unsigned v = pairs[base + i];
    int p = atomicAdd(&curl[v >> 16], 1);
    csrc[p] = (u16)(v & 0xFFFFu);
  }
}

// standalone gemm / qk / edge (sequential fallback + F4)
__global__ void __launch_bounds__(256) k_gemm(const float* __restrict__ A, const u16* __restrict__ Bt,
                                              const float* __restrict__ bias, u16* __restrict__ C) {
  __shared__ GemmSmem sm;
  gemm_body(sm, A, Bt, bias, C, blockIdx.x);
}

__global__ void __launch_bounds__(256) k_qk(
    const float* __restrict__ xu, const float* __restrict__ xi,
    const float* __restrict__ FW, const float* __restrict__ FB,
    float* __restrict__ K0, float* __restrict__ Q1, float* __restrict__ Q2,
    float* __restrict__ K2, float* __restrict__ Q0, float* __restrict__ K1) {
  qk_body(blockIdx.x, xu, xi, FW, FB, K0, Q1, Q2, K2, Q0, K1);
}

__global__ void __launch_bounds__(256) k_edge(
    const int* __restrict__ rp, const int* __restrict__ dg, const u16* __restrict__ csrc,
    const float* __restrict__ q, const float* __restrict__ k,
    const u16* __restrict__ hs, float* __restrict__ out, float scale, int accum) {
  __shared__ EdgeSmem sm;
  edge_body(sm, blockIdx.x, rp, dg, csrc, q, k, hs, out, scale, accum);
}

// fused: gemm (blocks [0,GEMMB)) + qk (blocks [GEMMB, GEMMB+QKB))
__global__ void __launch_bounds__(256) k_gemm_qk(
    const float* __restrict__ A, const u16* __restrict__ Bt, const float* __restrict__ bias,
    u16* __restrict__ C,
    const float* __restrict__ xu, const float* __restrict__ xi,
    const float* __restrict__ FW, const float* __restrict__ FB,
    float* __restrict__ K0, float* __restrict__ Q1, float* __restrict__ Q2,
    float* __restrict__ K2, float* __restrict__ Q0, float* __restrict__ K1) {
  __shared__ Smem sm;
  if ((int)blockIdx.x < GEMMB) gemm_body(sm.g, A, Bt, bias, C, blockIdx.x);
  else qk_body(blockIdx.x - GEMMB, xu, xi, FW, FB, K0, Q1, Q2, K2, Q0, K1);
}

// fused: gemm (blocks [0,GEMMB)) writing H_next + edge (rest) reading H_cur
__global__ void __launch_bounds__(256) k_edge_gemm(
    const int* __restrict__ rp, const int* __restrict__ dg, const u16* __restrict__ csrc,
    const float* __restrict__ q, const float* __restrict__ k,
    const u16* __restrict__ hread, float* __restrict__ out, float scale, int accum,
    const float* __restrict__ A, const u16* __restrict__ Bt, const float* __restrict__ bias,
    u16* __restrict__ hwrite) {
  __shared__ Smem sm;
  if ((int)blockIdx.x < GEMMB) gemm_body(sm.g, A, Bt, bias, hwrite, blockIdx.x);
  else edge_body(sm.e, blockIdx.x - GEMMB, rp, dg, csrc, q, k, hread, out, scale, accum);
}

extern "C" void kernel_launch(void* const* d_in, const int* in_sizes, int n_in,
                              void* d_out, int out_size, void* d_ws, size_t ws_size,
                              hipStream_t stream) {
  const float* xu = (const float*)d_in[0];
  const float* xi = (const float*)d_in[1];
  const float* Wv = (const float*)d_in[2];
  const float* bv = (const float*)d_in[3];
  const float* Wq = (const float*)d_in[4];
  const float* bq = (const float*)d_in[5];
  const float* Wk = (const float*)d_in[6];
  const float* bk = (const float*)d_in[7];
  const int* src1 = (const int*)d_in[8];
  const int* dst1 = (const int*)d_in[9];
  const int* src2 = (const int*)d_in[10];
  const int* dst2 = (const int*)d_in[11];
  const int* src3 = (const int*)d_in[12];
  const int* dst3 = (const int*)d_in[13];
  float* out_user = (float*)d_out;
  float* out_item = out_user + (size_t)NND * 64;

  char* w = (char*)d_ws;
  auto alloc = [&](size_t sz) -> char* {
    char* p = w; w += (sz + 255) & ~(size_t)255; return p;
  };
  // sequential prefix ~77 MB
  u16* H0    = (u16*)alloc((size_t)NND * 512 * 2);          // 51.2 MB
  u16* WT    = (u16*)alloc((size_t)3 * 512 * 256 * 2);      // 0.8 MB
  float* WVT = (float*)alloc((size_t)3 * 512 * 256 * 4);    // 1.6 MB
  float* FW  = (float*)alloc((size_t)3 * 16 * 256 * 4);
  float* FB  = (float*)alloc((size_t)3 * 16 * 4);
  float* Q0 = (float*)alloc((size_t)NND * 8 * 4);
  float* K0 = (float*)alloc((size_t)NND * 8 * 4);
  float* Q1 = (float*)alloc((size_t)NND * 8 * 4);
  float* K1 = (float*)alloc((size_t)NND * 8 * 4);
  float* Q2 = (float*)alloc((size_t)NND * 8 * 4);
  float* K2 = (float*)alloc((size_t)NND * 8 * 4);
  int* ROWPTR = (int*)alloc((size_t)3 * NND * 4);
  int* DEG    = (int*)alloc((size_t)3 * NND * 4);
  int* BCUR   = (int*)alloc(TOTB * 4);
  u16* CSRC   = (u16*)alloc((size_t)TOTB * CAPB * 2);      // 12.0 MB
  u16* H1     = (u16*)alloc((size_t)NND * 512 * 2);        // +51.2 MB (dual path only)
  size_t used_dual = (size_t)(w - (char*)d_ws);
  int dual = (ws_size == 0) || (ws_size >= used_dual);
  unsigned* PAIRS = (unsigned*)H0;                          // aliased; dead before H0 written
  (void)n_in; (void)in_sizes; (void)out_size;

  // --- common prep ---
  k_prepw<<<(3 * 512 * 256 + 255) / 256, 256, 0, stream>>>(Wv, WT, WVT, BCUR);
  kb_scatter<<<dim3((EDG + TS - 1) / TS, 3), 256, 0, stream>>>(src1, dst1, src2, dst2, src3, dst3, BCUR, PAIRS);
  kb_build<<<dim3(NBK, 3), 256, 0, stream>>>(PAIRS, BCUR, ROWPTR, DEG, CSRC);
  k_fusew2<<<48, 256, 0, stream>>>(WVT, bv, Wq, bq, Wk, bk, FW, FB);

  if (dual) {
    // F1: gemm rel0 (xu -> H0)  ||  qk
    k_gemm_qk<<<GEMMB + QKB, 256, 0, stream>>>(xu, WT, bv, H0,
                                               xu, xi, FW, FB, K0, Q1, Q2, K2, Q0, K1);
    // F2: edge rel0 (H0)  ||  gemm rel1 (xi -> H1)
    k_edge_gemm<<<GEMMB + EDGEB, 256, 0, stream>>>(ROWPTR, DEG, CSRC, Q0, K0, H0, out_item, 0.125f, 0,
                                                   xi, WT + 512 * 256, bv + 512, H1);
    // F3: edge rel1 (H1)  ||  gemm rel2 (xu -> H0)
    k_edge_gemm<<<GEMMB + EDGEB, 256, 0, stream>>>(ROWPTR + NND, DEG + NND, CSRC, Q1, K1, H1, out_user, 0.0625f, 0,
                                                   xu, WT + 2 * 512 * 256, bv + 1024, H0);
    // F4: edge rel2 (H0)
    k_edge<<<EDGEB, 256, 0, stream>>>(ROWPTR + 2 * NND, DEG + 2 * NND, CSRC, Q2, K2, H0, out_user, 0.0625f, 1);
  } else {
    // sequential fallback (round-12 proven path, single H)
    k_qk<<<GEMMB ? 1536 : 1536, 256, 0, stream>>>(xu, xi, FW, FB, K0, Q1, Q2, K2, Q0, K1);
    k_gemm<<<GEMMB, 256, 0, stream>>>(xu, WT, bv, H0);
    k_edge<<<EDGEB, 256, 0, stream>>>(ROWPTR, DEG, CSRC, Q0, K0, H0, out_item, 0.125f, 0);
    k_gemm<<<GEMMB, 256, 0, stream>>>(xi, WT + 512 * 256, bv + 512, H0);
    k_edge<<<EDGEB, 256, 0, stream>>>(ROWPTR + NND, DEG + NND, CSRC, Q1, K1, H0, out_user, 0.0625f, 0);
    k_gemm<<<GEMMB, 256, 0, stream>>>(xu, WT + 2 * 512 * 256, bv + 1024, H0);
    k_edge<<<EDGEB, 256, 0, stream>>>(ROWPTR + 2 * NND, DEG + 2 * NND, CSRC, Q2, K2, H0, out_user, 0.0625f, 1);
  }
}

// Round 14
// 1254.611 us; speedup vs baseline: 1.7270x; 1.7270x over previous
//
#include <hip/hip_runtime.h>

typedef unsigned short u16;
typedef __attribute__((ext_vector_type(4))) float f32x4;
typedef __attribute__((ext_vector_type(8))) short s16x8;

#define NND 50000      // nodes per side (NU == NI)
#define EDG 1600000    // edges per relation
#define NBK 391        // buckets per relation = ceil(NND/128)
#define TOTB (3 * NBK)
#define TS 4096        // edges per scatter tile
#define CAPB 5120      // fixed bucket capacity (mean 4092, sd 64 -> +16 sigma)
#define SAST 264       // sA row stride in u16 (528B -> 2-way max bank conflict)

__device__ __forceinline__ u16 f2b(float f) {
  union { float f; unsigned u; } c; c.f = f;
  unsigned r = c.u + 0x7fff + ((c.u >> 16) & 1);   // RNE
  return (u16)(r >> 16);
}

// paired bf16 decode + 8-wide FMA into num[8]
__device__ __forceinline__ void accum8(float* num, uint4 u, float4 w0, float4 w1) {
  num[0] += w0.x * __int_as_float((int)(u.x << 16));
  num[1] += w0.y * __int_as_float((int)(u.x & 0xFFFF0000u));
  num[2] += w0.z * __int_as_float((int)(u.y << 16));
  num[3] += w0.w * __int_as_float((int)(u.y & 0xFFFF0000u));
  num[4] += w1.x * __int_as_float((int)(u.z << 16));
  num[5] += w1.y * __int_as_float((int)(u.z & 0xFFFF0000u));
  num[6] += w1.z * __int_as_float((int)(u.w << 16));
  num[7] += w1.w * __int_as_float((int)(u.w & 0xFFFF0000u));
}

// ---------------- weight prep: WT (bf16 transpose), WVT (fp32 transpose), bucket cursors ----------------
__global__ void k_prepw(const float* __restrict__ Wv, u16* __restrict__ Wt,
                        float* __restrict__ Wvt, int* __restrict__ bcur) {
  int tid = blockIdx.x * 256 + threadIdx.x;
  if (tid < 3 * 512 * 256) {
    int r = tid / (512 * 256); int rem = tid - r * 512 * 256;
    int n = rem >> 8; int kk = rem & 255;
    float v = Wv[((size_t)r * 256 + kk) * 512 + n];
    Wt[tid] = f2b(v);
    Wvt[tid] = v;
  }
  if (tid < TOTB) bcur[tid] = tid * CAPB;
}

// ---------------- fused q/k weights from WVT (coalesced) ----------------
__global__ void __launch_bounds__(256) k_fusew2(
    const float* __restrict__ Wvt, const float* __restrict__ bv,
    const float* __restrict__ Wq, const float* __restrict__ bq,
    const float* __restrict__ Wk, const float* __restrict__ bk,
    float* __restrict__ FW, float* __restrict__ FB) {
  __shared__ float red[256];
  int r = blockIdx.x >> 4, o = blockIdx.x & 15;
  int t = threadIdx.x;
  const float* wvt = Wvt + (size_t)r * 512 * 256;
  const float* wqk = (o < 8) ? (Wq + (size_t)r * 512 * 8 + o) : (Wk + (size_t)r * 512 * 8 + (o - 8));
  float acc = 0.f;
#pragma unroll 8
  for (int j = 0; j < 512; j++) acc += wvt[(size_t)j * 256 + t] * wqk[j * 8];
  FW[((size_t)r * 16 + o) * 256 + t] = acc;
  float pb = 0.f;
  for (int j = t; j < 512; j += 256) pb += bv[r * 512 + j] * wqk[j * 8];
  red[t] = pb;
  __syncthreads();
  for (int off = 128; off > 0; off >>= 1) {
    if (t < off) red[t] += red[t + off];
    __syncthreads();
  }
  if (t == 0) {
    float b = (o < 8) ? bq[r * 8 + o] : bk[r * 8 + (o - 8)];
    FB[r * 16 + o] = red[0] + b;
  }
}

// ================= CSR build: fixed-capacity bucket regions =================
__global__ void __launch_bounds__(256) kb_scatter(
    const int* __restrict__ s1, const int* __restrict__ d1,
    const int* __restrict__ s2, const int* __restrict__ d2,
    const int* __restrict__ s3, const int* __restrict__ d3,
    int* __restrict__ BCUR, unsigned* __restrict__ pairs) {
  __shared__ int h[NBK];
  __shared__ int bbase[NBK];
  int tid = threadIdx.x;
  int r = blockIdx.y;
  const int* dp = (r == 0) ? d1 : (r == 1) ? d2 : d3;
  const int* sp = (r == 0) ? s1 : (r == 1) ? s2 : s3;
  int e0 = blockIdx.x * TS;
  int n = EDG - e0; if (n > TS) n = TS;
  for (int b = tid; b < NBK; b += 256) h[b] = 0;
  __syncthreads();
  int eb[16]; unsigned ev[16];
#pragma unroll
  for (int k = 0; k < 16; k++) {
    int i = k * 256 + tid;
    if (i < n) {
      int d = dp[e0 + i], ss = sp[e0 + i];
      eb[k] = d >> 7;
      ev[k] = ((unsigned)(d & 127) << 16) | (unsigned)ss;
      atomicAdd(&h[eb[k]], 1);
    } else eb[k] = -1;
  }
  __syncthreads();
  for (int b = tid; b < NBK; b += 256) {
    int c = h[b];
    bbase[b] = c ? atomicAdd(&BCUR[r * NBK + b], c) : 0;
  }
  __syncthreads();
  for (int b = tid; b < NBK; b += 256) h[b] = 0;   // reuse as local cursor
  __syncthreads();
#pragma unroll
  for (int k = 0; k < 16; k++) {
    if (eb[k] >= 0) {
      int off = atomicAdd(&h[eb[k]], 1);
      int pos = bbase[eb[k]] + off;
      int limit = (r * NBK + eb[k] + 1) * CAPB;
      if (pos < limit) pairs[pos] = ev[k];     // 16-sigma guard vs OOB
    }
  }
}

// -- per-bucket: group into csrc (u16) + emit rp (absolute, padded space) and deg --
__global__ void __launch_bounds__(256) kb_build(
    const unsigned* __restrict__ pairs, const int* __restrict__ BCUR,
    int* __restrict__ rp, int* __restrict__ dgarr, u16* __restrict__ csrc) {
  __shared__ int cntl[128];
  __shared__ int sc[128];
  __shared__ int curl[128];
  int t = threadIdx.x;
  int r = blockIdx.y, bx = blockIdx.x;
  int bin = r * NBK + bx;
  int base = bin * CAPB;
  int cnt = BCUR[bin] - base; if (cnt > CAPB) cnt = CAPB;
  int node0 = bx << 7;
  int nloc = NND - node0; if (nloc > 128) nloc = 128;
  if (t < 128) cntl[t] = 0;
  __syncthreads();
  for (int i = t; i < cnt; i += 256)
    atomicAdd(&cntl[pairs[base + i] >> 16], 1);
  __syncthreads();
  if (t < 128) sc[t] = cntl[t];
  __syncthreads();
  for (int off = 1; off < 128; off <<= 1) {
    int v = 0;
    if (t < 128) { v = sc[t]; if (t >= off) v += sc[t - off]; }
    __syncthreads();
    if (t < 128) sc[t] = v;
    __syncthreads();
  }
  if (t < 128) {
    int excl = sc[t] - cntl[t];
    if (t < nloc) { rp[r * NND + node0 + t] = base + excl; dgarr[r * NND + node0 + t] = cntl[t]; }
    curl[t] = base + excl;
  }
  __syncthreads();
  for (int i = t; i < cnt; i += 256) {
    unsigned v = pairs[base + i];
    int p = atomicAdd(&curl[v >> 16], 1);
    csrc[p] = (u16)(v & 0xFFFFu);
  }
}

// ---------------- bf16 MFMA GEMM, A staged once per M-block, 4 N-tiles in-block ----------------
// H[M][f*8+h] = bf16(A_f32[M,256] @ Wv + bv)  (head-transposed); grid = 391 M-blocks
__global__ void __launch_bounds__(256) k_gemm(const float* __restrict__ A, const u16* __restrict__ Bt,
                                              const float* __restrict__ bias, u16* __restrict__ C) {
  __shared__ u16 sA[128 * SAST];   // 67.6 KB: full 128x256 A-block (bf16), staged ONCE
  __shared__ u16 sB[128 * 72];     // 18.4 KB: one 128x64 B-tile
  int tid = threadIdx.x;
  int lane = tid & 63, wid = tid >> 6;
  int wm = wid >> 1, wn = wid & 1;
  int l15 = lane & 15, l4 = lane >> 4;
  int m0 = blockIdx.x * 128;
  // stage A once: 128*256/8 = 4096 chunks / 256 threads = 16 each
#pragma unroll
  for (int p = 0; p < 16; p++) {
    int idx = p * 256 + tid;
    int row = idx >> 5, seg = idx & 31;
    int gm = m0 + row; if (gm >= NND) gm = NND - 1;
    float4 a0 = *(const float4*)(A + (size_t)gm * 256 + seg * 8);
    float4 a1 = *(const float4*)(A + (size_t)gm * 256 + seg * 8 + 4);
    s16x8 av;
    av[0] = (short)f2b(a0.x); av[1] = (short)f2b(a0.y);
    av[2] = (short)f2b(a0.z); av[3] = (short)f2b(a0.w);
    av[4] = (short)f2b(a1.x); av[5] = (short)f2b(a1.y);
    av[6] = (short)f2b(a1.z); av[7] = (short)f2b(a1.w);
    *(s16x8*)&sA[row * SAST + seg * 8] = av;
  }
  __syncthreads();
  for (int nt = 0; nt < 4; nt++) {
    int n0 = nt * 128;
    f32x4 acc[4][4] = {};
    for (int ko = 0; ko < 256; ko += 64) {
      // stage B tile [128x64]: 1024 chunks / 256 threads = 4 each (L2-hot, 0.26MB panel)
#pragma unroll
      for (int p = 0; p < 4; p++) {
        int idx = p * 256 + tid;
        int row = idx >> 3, seg = idx & 7;
        *(s16x8*)&sB[row * 72 + seg * 8] = *(const s16x8*)(Bt + (size_t)(n0 + row) * 256 + ko + seg * 8);
      }
      __syncthreads();
#pragma unroll
      for (int kk = 0; kk < 2; kk++) {
        s16x8 af[4], bf[4];
#pragma unroll
        for (int i = 0; i < 4; i++) af[i] = *(const s16x8*)&sA[(wm * 64 + i * 16 + l15) * SAST + ko + kk * 32 + l4 * 8];
#pragma unroll
        for (int j = 0; j < 4; j++) bf[j] = *(const s16x8*)&sB[(wn * 64 + j * 16 + l15) * 72 + kk * 32 + l4 * 8];
#pragma unroll
        for (int i = 0; i < 4; i++)
#pragma unroll
          for (int j = 0; j < 4; j++)
            acc[i][j] = __builtin_amdgcn_mfma_f32_16x16x32_bf16(af[i], bf[j], acc[i][j], 0, 0, 0);
      }
      __syncthreads();
    }
    // epilogue for this N-tile (registers + global only; no sB read)
#pragma unroll
    for (int j = 0; j < 4; j++) {
      int n = n0 + wn * 64 + j * 16 + l15;
      float bb = bias[n];
      int tpos = ((n & 63) << 3) + (n >> 6);          // head-transposed column
#pragma unroll
      for (int i = 0; i < 4; i++) {
        int mb = m0 + wm * 64 + i * 16 + l4 * 4;
#pragma unroll
        for (int r = 0; r < 4; r++) {
          int m = mb + r;
          if (m < NND) C[(size_t)m * 512 + tpos] = f2b(acc[i][j][r] + bb);
        }
      }
    }
  }
}

// ---------------- q/k logits (merged xu+xi passes) ----------------
__global__ void __launch_bounds__(256) k_qk(
    const float* __restrict__ xu, const float* __restrict__ xi,
    const float* __restrict__ FW, const float* __restrict__ FB,
    float* __restrict__ K0, float* __restrict__ Q1, float* __restrict__ Q2,
    float* __restrict__ K2, float* __restrict__ Q0, float* __restrict__ K1) {
  int lane = threadIdx.x & 63, wid = threadIdx.x >> 6;
  if (blockIdx.x < 1024) {
    int stride = 1024 * 4;
    for (int row = blockIdx.x * 4 + wid; row < NND; row += stride) {
      float4 xv = *(const float4*)(xu + (size_t)row * 256 + lane * 4);
      {
        float p[16];
#pragma unroll
        for (int c = 0; c < 16; c++) {
          const float4 wv = *(const float4*)(FW + (size_t)(8 + c) * 256 + lane * 4);
          p[c] = xv.x * wv.x + xv.y * wv.y + xv.z * wv.z + xv.w * wv.w;
        }
#pragma unroll
        for (int off = 1; off < 64; off <<= 1)
#pragma unroll
          for (int c = 0; c < 16; c++) p[c] += __shfl_xor(p[c], off, 64);
        if (lane == 0) {
#pragma unroll
          for (int c = 0; c < 8; c++) K0[row * 8 + c] = p[c] + FB[8 + c];
#pragma unroll
          for (int c = 0; c < 8; c++) Q1[row * 8 + c] = p[8 + c] + FB[16 + c];
        }
      }
      {
        float p[16];
#pragma unroll
        for (int c = 0; c < 16; c++) {
          const float4 wv = *(const float4*)(FW + (size_t)(32 + c) * 256 + lane * 4);
          p[c] = xv.x * wv.x + xv.y * wv.y + xv.z * wv.z + xv.w * wv.w;
        }
#pragma unroll
        for (int off = 1; off < 64; off <<= 1)
#pragma unroll
          for (int c = 0; c < 16; c++) p[c] += __shfl_xor(p[c], off, 64);
        if (lane == 0) {
#pragma unroll
          for (int c = 0; c < 8; c++) Q2[row * 8 + c] = p[c] + FB[32 + c];
#pragma unroll
          for (int c = 0; c < 8; c++) K2[row * 8 + c] = p[8 + c] + FB[40 + c];
        }
      }
    }
  } else {
    int b = blockIdx.x - 1024;
    int stride = 512 * 4;
    for (int row = b * 4 + wid; row < NND; row += stride) {
      float4 xv = *(const float4*)(xi + (size_t)row * 256 + lane * 4);
      float p[16];
#pragma unroll
      for (int c = 0; c < 16; c++) {
        const float4 wv = *(const float4*)(FW + (size_t)((c < 8) ? c : (16 + c)) * 256 + lane * 4);
        p[c] = xv.x * wv.x + xv.y * wv.y + xv.z * wv.z + xv.w * wv.w;
      }
#pragma unroll
      for (int off = 1; off < 64; off <<= 1)
#pragma unroll
        for (int c = 0; c < 16; c++) p[c] += __shfl_xor(p[c], off, 64);
      if (lane == 0) {
#pragma unroll
        for (int c = 0; c < 8; c++) Q0[row * 8 + c] = p[c] + FB[c];
#pragma unroll
        for (int c = 0; c < 8; c++) K1[row * 8 + c] = p[8 + c] + FB[24 + c];
      }
    }
  }
}

// ---------------- edge aggregation: single-pass, 2 waves/dst, 4x-unrolled gather ----------------
__global__ void __launch_bounds__(256) k_edge(
    const int* __restrict__ rp, const int* __restrict__ dg, const u16* __restrict__ csrc,
    const float* __restrict__ q, const float* __restrict__ k,
    const u16* __restrict__ hs, float* __restrict__ out,
    float scale, int accum) {
  __shared__ float exw[4][64 * 8];
  __shared__ int sarr[4][64];
  __shared__ float sd[4][8];
  __shared__ float sacc[4][64];
  int lane = threadIdx.x & 63, w = threadIdx.x >> 6;
  int dst = blockIdx.x * 2 + (w >> 1);
  int half = w & 1;
  int beg = rp[dst];
  int deg = dg[dst];
  int hlen = (deg + 1) >> 1;
  int s0 = half ? hlen : 0;
  int s1 = half ? deg : hlen;
  float qv[8];
  {
    float4 q0 = *(const float4*)(q + dst * 8);
    float4 q1 = *(const float4*)(q + dst * 8 + 4);
    qv[0] = q0.x; qv[1] = q0.y; qv[2] = q0.z; qv[3] = q0.w;
    qv[4] = q1.x; qv[5] = q1.y; qv[6] = q1.z; qv[7] = q1.w;
  }
  float num[8] = {0, 0, 0, 0, 0, 0, 0, 0};
  float dsum[8] = {0, 0, 0, 0, 0, 0, 0, 0};
  for (int base = s0; base < s1; base += 64) {
    int i = base + lane;
    int nn = min(64, s1 - base);
    if (i < s1) {
      int s = (int)csrc[beg + i];
      sarr[w][lane] = s;
      float4 k0 = *(const float4*)(k + s * 8);
      float4 k1 = *(const float4*)(k + s * 8 + 4);
      float kv[8] = {k0.x, k0.y, k0.z, k0.w, k1.x, k1.y, k1.z, k1.w};
#pragma unroll
      for (int h = 0; h < 8; h++) {
        float e = qv[h] + kv[h];
        e = e > 0.f ? e : 0.2f * e;
        float wgt = exp2f(e * 1.44269504f);
        exw[w][lane * 8 + h] = wgt;
        dsum[h] += wgt;
      }
    }
    __asm__ __volatile__("s_waitcnt lgkmcnt(0)" ::: "memory");
    int j = 0;
    for (; j + 4 <= nn; j += 4) {
      int sa = sarr[w][j], sb = sarr[w][j + 1], sc = sarr[w][j + 2], sdn = sarr[w][j + 3];
      uint4 ua = *(const uint4*)(hs + (size_t)sa * 512 + lane * 8);
      uint4 ub = *(const uint4*)(hs + (size_t)sb * 512 + lane * 8);
      uint4 uc = *(const uint4*)(hs + (size_t)sc * 512 + lane * 8);
      uint4 ud = *(const uint4*)(hs + (size_t)sdn * 512 + lane * 8);
      float4 wa0 = *(const float4*)&exw[w][j * 8],       wa1 = *(const float4*)&exw[w][j * 8 + 4];
      float4 wb0 = *(const float4*)&exw[w][j * 8 + 8],   wb1 = *(const float4*)&exw[w][j * 8 + 12];
      float4 wc0 = *(const float4*)&exw[w][j * 8 + 16],  wc1 = *(const float4*)&exw[w][j * 8 + 20];
      float4 wd0 = *(const float4*)&exw[w][j * 8 + 24],  wd1 = *(const float4*)&exw[w][j * 8 + 28];
      accum8(num, ua, wa0, wa1);
      accum8(num, ub, wb0, wb1);
      accum8(num, uc, wc0, wc1);
      accum8(num, ud, wd0, wd1);
    }
    for (; j < nn; j++) {
      int s = sarr[w][j];
      uint4 u = *(const uint4*)(hs + (size_t)s * 512 + lane * 8);
      float4 e0 = *(const float4*)&exw[w][j * 8];
      float4 e1 = *(const float4*)&exw[w][j * 8 + 4];
      accum8(num, u, e0, e1);
    }
  }
#pragma unroll
  for (int off = 1; off < 64; off <<= 1)
#pragma unroll
    for (int h = 0; h < 8; h++) dsum[h] += __shfl_xor(dsum[h], off, 64);
  if (lane == 0) {
#pragma unroll
    for (int h = 0; h < 8; h++) sd[w][h] = dsum[h];
  }
  __syncthreads();
  float acc = 0.f;
#pragma unroll
  for (int h = 0; h < 8; h++) {
    float tot = sd[w][h] + sd[w ^ 1][h];
    float rden = tot > 0.f ? 1.f / tot : 0.f;
    acc += num[h] * rden;
  }
  acc *= scale;
  sacc[w][lane] = acc;
  __syncthreads();
  if (half == 0) {
    float tot = sacc[w][lane] + sacc[w + 1][lane];
    if (accum) out[dst * 64 + lane] += tot;
    else out[dst * 64 + lane] = tot;
  }
}

extern "C" void kernel_launch(void* const* d_in, const int* in_sizes, int n_in,
                              void* d_out, int out_size, void* d_ws, size_t ws_size,
                              hipStream_t stream) {
  const float* xu = (const float*)d_in[0];
  const float* xi = (const float*)d_in[1];
  const float* Wv = (const float*)d_in[2];
  const float* bv = (const float*)d_in[3];
  const float* Wq = (const float*)d_in[4];
  const float* bq = (const float*)d_in[5];
  const float* Wk = (const float*)d_in[6];
  const float* bk = (const float*)d_in[7];
  const int* src1 = (const int*)d_in[8];
  const int* dst1 = (const int*)d_in[9];
  const int* src2 = (const int*)d_in[10];
  const int* dst2 = (const int*)d_in[11];
  const int* src3 = (const int*)d_in[12];
  const int* dst3 = (const int*)d_in[13];
  float* out_user = (float*)d_out;
  float* out_item = out_user + (size_t)NND * 64;

  char* w = (char*)d_ws;
  auto alloc = [&](size_t sz) -> char* {
    char* p = w; w += (sz + 255) & ~(size_t)255; return p;
  };
  // total ~77 MB (round-12 proven layout)
  u16* H     = (u16*)alloc((size_t)NND * 512 * 2);          // 51.2 MB shared h table
  u16* WT    = (u16*)alloc((size_t)3 * 512 * 256 * 2);      // 0.8 MB
  float* WVT = (float*)alloc((size_t)3 * 512 * 256 * 4);    // 1.6 MB fp32 transpose
  float* FW  = (float*)alloc((size_t)3 * 16 * 256 * 4);     // fused qk weights
  float* FB  = (float*)alloc((size_t)3 * 16 * 4);
  float* Q0 = (float*)alloc((size_t)NND * 8 * 4);
  float* K0 = (float*)alloc((size_t)NND * 8 * 4);
  float* Q1 = (float*)alloc((size_t)NND * 8 * 4);
  float* K1 = (float*)alloc((size_t)NND * 8 * 4);
  float* Q2 = (float*)alloc((size_t)NND * 8 * 4);
  float* K2 = (float*)alloc((size_t)NND * 8 * 4);
  int* ROWPTR = (int*)alloc((size_t)3 * NND * 4);
  int* DEG    = (int*)alloc((size_t)3 * NND * 4);
  int* BCUR   = (int*)alloc(TOTB * 4);
  u16* CSRC   = (u16*)alloc((size_t)TOTB * CAPB * 2);      // 12.0 MB padded u16
  unsigned* PAIRS = (unsigned*)H;                          // aliased (24 MB < 51.2 MB); dead before H written
  (void)ws_size; (void)n_in; (void)in_sizes; (void)out_size;

  // --- weight prep (+ bucket cursor init) ---
  k_prepw<<<(3 * 512 * 256 + 255) / 256, 256, 0, stream>>>(Wv, WT, WVT, BCUR);

  // --- CSR build (fixed-capacity buckets: scatter + group only) ---
  kb_scatter<<<dim3((EDG + TS - 1) / TS, 3), 256, 0, stream>>>(src1, dst1, src2, dst2, src3, dst3, BCUR, PAIRS);
  kb_build<<<dim3(NBK, 3), 256, 0, stream>>>(PAIRS, BCUR, ROWPTR, DEG, CSRC);

  // --- fused q/k weights + logits ---
  k_fusew2<<<48, 256, 0, stream>>>(WVT, bv, Wq, bq, Wk, bk, FW, FB);
  k_qk<<<1536, 256, 0, stream>>>(xu, xi, FW, FB, K0, Q1, Q2, K2, Q0, K1);

  // --- per relation: GEMM into shared H (A staged once, 4 N-tiles/block), then edge ---
  k_gemm<<<NBK, 256, 0, stream>>>(xu, WT, bv, H);
  k_edge<<<NND / 2, 256, 0, stream>>>(ROWPTR, DEG, CSRC, Q0, K0, H, out_item, 0.125f, 0);
  k_gemm<<<NBK, 256, 0, stream>>>(xi, WT + 512 * 256, bv + 512, H);
  k_edge<<<NND / 2, 256, 0, stream>>>(ROWPTR + NND, DEG + NND, CSRC, Q1, K1, H, out_user, 0.0625f, 0);
  k_gemm<<<NBK, 256, 0, stream>>>(xu, WT + 2 * 512 * 256, bv + 1024, H);
  k_edge<<<NND / 2, 256, 0, stream>>>(ROWPTR + 2 * NND, DEG + 2 * NND, CSRC, Q2, K2, H, out_user, 0.0625f, 1);
}

// Round 15
// 1191.865 us; speedup vs baseline: 1.8179x; 1.0526x over previous
//
#include <hip/hip_runtime.h>

typedef unsigned short u16;
typedef __attribute__((ext_vector_type(4))) float f32x4;
typedef __attribute__((ext_vector_type(8))) short s16x8;

#define NND 50000      // nodes per side (NU == NI)
#define EDG 1600000    // edges per relation
#define NBK 391        // buckets per relation = ceil(NND/128)
#define TOTB (3 * NBK)
#define TS 4096        // edges per scatter tile
#define CAPB 5120      // fixed bucket capacity (mean 4092, sd 64 -> +16 sigma)

__device__ __forceinline__ u16 f2b(float f) {
  union { float f; unsigned u; } c; c.f = f;
  unsigned r = c.u + 0x7fff + ((c.u >> 16) & 1);   // RNE
  return (u16)(r >> 16);
}

// paired bf16 decode + 8-wide FMA into num[8]
__device__ __forceinline__ void accum8(float* num, uint4 u, float4 w0, float4 w1) {
  num[0] += w0.x * __int_as_float((int)(u.x << 16));
  num[1] += w0.y * __int_as_float((int)(u.x & 0xFFFF0000u));
  num[2] += w0.z * __int_as_float((int)(u.y << 16));
  num[3] += w0.w * __int_as_float((int)(u.y & 0xFFFF0000u));
  num[4] += w1.x * __int_as_float((int)(u.z << 16));
  num[5] += w1.y * __int_as_float((int)(u.z & 0xFFFF0000u));
  num[6] += w1.z * __int_as_float((int)(u.w << 16));
  num[7] += w1.w * __int_as_float((int)(u.w & 0xFFFF0000u));
}

// ---------------- weight prep: WT (bf16 transpose), WVT (fp32 transpose), bucket cursors ----------------
__global__ void k_prepw(const float* __restrict__ Wv, u16* __restrict__ Wt,
                        float* __restrict__ Wvt, int* __restrict__ bcur) {
  int tid = blockIdx.x * 256 + threadIdx.x;
  if (tid < 3 * 512 * 256) {
    int r = tid / (512 * 256); int rem = tid - r * 512 * 256;
    int n = rem >> 8; int kk = rem & 255;
    float v = Wv[((size_t)r * 256 + kk) * 512 + n];
    Wt[tid] = f2b(v);
    Wvt[tid] = v;
  }
  if (tid < TOTB) bcur[tid] = tid * CAPB;
}

// ---------------- fused q/k weights from WVT (coalesced) ----------------
__global__ void __launch_bounds__(256) k_fusew2(
    const float* __restrict__ Wvt, const float* __restrict__ bv,
    const float* __restrict__ Wq, const float* __restrict__ bq,
    const float* __restrict__ Wk, const float* __restrict__ bk,
    float* __restrict__ FW, float* __restrict__ FB) {
  __shared__ float red[256];
  int r = blockIdx.x >> 4, o = blockIdx.x & 15;
  int t = threadIdx.x;
  const float* wvt = Wvt + (size_t)r * 512 * 256;
  const float* wqk = (o < 8) ? (Wq + (size_t)r * 512 * 8 + o) : (Wk + (size_t)r * 512 * 8 + (o - 8));
  float acc = 0.f;
#pragma unroll 8
  for (int j = 0; j < 512; j++) acc += wvt[(size_t)j * 256 + t] * wqk[j * 8];
  FW[((size_t)r * 16 + o) * 256 + t] = acc;
  float pb = 0.f;
  for (int j = t; j < 512; j += 256) pb += bv[r * 512 + j] * wqk[j * 8];
  red[t] = pb;
  __syncthreads();
  for (int off = 128; off > 0; off >>= 1) {
    if (t < off) red[t] += red[t + off];
    __syncthreads();
  }
  if (t == 0) {
    float b = (o < 8) ? bq[r * 8 + o] : bk[r * 8 + (o - 8)];
    FB[r * 16 + o] = red[0] + b;
  }
}

// ================= CSR build: fixed-capacity bucket regions =================
__global__ void __launch_bounds__(256) kb_scatter(
    const int* __restrict__ s1, const int* __restrict__ d1,
    const int* __restrict__ s2, const int* __restrict__ d2,
    const int* __restrict__ s3, const int* __restrict__ d3,
    int* __restrict__ BCUR, unsigned* __restrict__ pairs) {
  __shared__ int h[NBK];
  __shared__ int bbase[NBK];
  int tid = threadIdx.x;
  int r = blockIdx.y;
  const int* dp = (r == 0) ? d1 : (r == 1) ? d2 : d3;
  const int* sp = (r == 0) ? s1 : (r == 1) ? s2 : s3;
  int e0 = blockIdx.x * TS;
  int n = EDG - e0; if (n > TS) n = TS;
  for (int b = tid; b < NBK; b += 256) h[b] = 0;
  __syncthreads();
  int eb[16]; unsigned ev[16];
#pragma unroll
  for (int k = 0; k < 16; k++) {
    int i = k * 256 + tid;
    if (i < n) {
      int d = dp[e0 + i], ss = sp[e0 + i];
      eb[k] = d >> 7;
      ev[k] = ((unsigned)(d & 127) << 16) | (unsigned)ss;
      atomicAdd(&h[eb[k]], 1);
    } else eb[k] = -1;
  }
  __syncthreads();
  for (int b = tid; b < NBK; b += 256) {
    int c = h[b];
    bbase[b] = c ? atomicAdd(&BCUR[r * NBK + b], c) : 0;
  }
  __syncthreads();
  for (int b = tid; b < NBK; b += 256) h[b] = 0;   // reuse as local cursor
  __syncthreads();
#pragma unroll
  for (int k = 0; k < 16; k++) {
    if (eb[k] >= 0) {
      int off = atomicAdd(&h[eb[k]], 1);
      int pos = bbase[eb[k]] + off;
      int limit = (r * NBK + eb[k] + 1) * CAPB;
      if (pos < limit) pairs[pos] = ev[k];     // 16-sigma guard vs OOB
    }
  }
}

// -- per-bucket: group into csrc (u16) + emit rp (absolute, padded space) and deg --
__global__ void __launch_bounds__(256) kb_build(
    const unsigned* __restrict__ pairs, const int* __restrict__ BCUR,
    int* __restrict__ rp, int* __restrict__ dgarr, u16* __restrict__ csrc) {
  __shared__ int cntl[128];
  __shared__ int sc[128];
  __shared__ int curl[128];
  int t = threadIdx.x;
  int r = blockIdx.y, bx = blockIdx.x;
  int bin = r * NBK + bx;
  int base = bin * CAPB;
  int cnt = BCUR[bin] - base; if (cnt > CAPB) cnt = CAPB;
  int node0 = bx << 7;
  int nloc = NND - node0; if (nloc > 128) nloc = 128;
  if (t < 128) cntl[t] = 0;
  __syncthreads();
  for (int i = t; i < cnt; i += 256)
    atomicAdd(&cntl[pairs[base + i] >> 16], 1);
  __syncthreads();
  if (t < 128) sc[t] = cntl[t];
  __syncthreads();
  for (int off = 1; off < 128; off <<= 1) {
    int v = 0;
    if (t < 128) { v = sc[t]; if (t >= off) v += sc[t - off]; }
    __syncthreads();
    if (t < 128) sc[t] = v;
    __syncthreads();
  }
  if (t < 128) {
    int excl = sc[t] - cntl[t];
    if (t < nloc) { rp[r * NND + node0 + t] = base + excl; dgarr[r * NND + node0 + t] = cntl[t]; }
    curl[t] = base + excl;
  }
  __syncthreads();
  for (int i = t; i < cnt; i += 256) {
    unsigned v = pairs[base + i];
    int p = atomicAdd(&curl[v >> 16], 1);
    csrc[p] = (u16)(v & 0xFFFFu);
  }
}

// ---------------- bf16 MFMA GEMM, BK=64 (round-12 shape; grid dim3(4, NBK): N fast, M slow) ----------------
// The 4 N-tile blocks of one M-block are dispatch-adjacent -> A row-block read once from HBM, 3x from L2.
__global__ void __launch_bounds__(256) k_gemm(const float* __restrict__ A, const u16* __restrict__ Bt,
                                              const float* __restrict__ bias, u16* __restrict__ C) {
  __shared__ u16 sA[128 * 72];   // 128 rows x 64 cols, stride 72 (144B: 16B-aligned, 2-way max conflict)
  __shared__ u16 sB[128 * 72];
  int tid = threadIdx.x;
  int lane = tid & 63, wid = tid >> 6;
  int wm = wid >> 1, wn = wid & 1;
  int l15 = lane & 15, l4 = lane >> 4;
  int m0 = blockIdx.y * 128, n0 = blockIdx.x * 128;
  f32x4 acc[4][4] = {};
  for (int ko = 0; ko < 256; ko += 64) {
#pragma unroll
    for (int p = 0; p < 4; p++) {
      int idx = p * 256 + tid;          // 1024 chunks of 8 elems
      int row = idx >> 3, seg = idx & 7;
      int gm = m0 + row; if (gm >= NND) gm = NND - 1;
      float4 a0 = *(const float4*)(A + (size_t)gm * 256 + ko + seg * 8);
      float4 a1 = *(const float4*)(A + (size_t)gm * 256 + ko + seg * 8 + 4);
      s16x8 av;
      av[0] = (short)f2b(a0.x); av[1] = (short)f2b(a0.y);
      av[2] = (short)f2b(a0.z); av[3] = (short)f2b(a0.w);
      av[4] = (short)f2b(a1.x); av[5] = (short)f2b(a1.y);
      av[6] = (short)f2b(a1.z); av[7] = (short)f2b(a1.w);
      *(s16x8*)&sA[row * 72 + seg * 8] = av;
      *(s16x8*)&sB[row * 72 + seg * 8] = *(const s16x8*)(Bt + (size_t)(n0 + row) * 256 + ko + seg * 8);
    }
    __syncthreads();
#pragma unroll
    for (int kk = 0; kk < 2; kk++) {
      s16x8 af[4], bf[4];
#pragma unroll
      for (int i = 0; i < 4; i++) af[i] = *(const s16x8*)&sA[(wm * 64 + i * 16 + l15) * 72 + kk * 32 + l4 * 8];
#pragma unroll
      for (int j = 0; j < 4; j++) bf[j] = *(const s16x8*)&sB[(wn * 64 + j * 16 + l15) * 72 + kk * 32 + l4 * 8];
#pragma unroll
      for (int i = 0; i < 4; i++)
#pragma unroll
        for (int j = 0; j < 4; j++)
          acc[i][j] = __builtin_amdgcn_mfma_f32_16x16x32_bf16(af[i], bf[j], acc[i][j], 0, 0, 0);
    }
    __syncthreads();
  }
#pragma unroll
  for (int j = 0; j < 4; j++) {
    int n = n0 + wn * 64 + j * 16 + l15;
    float bb = bias[n];
    int tpos = ((n & 63) << 3) + (n >> 6);          // head-transposed column
#pragma unroll
    for (int i = 0; i < 4; i++) {
      int mb = m0 + wm * 64 + i * 16 + l4 * 4;
#pragma unroll
      for (int r = 0; r < 4; r++) {
        int m = mb + r;
        if (m < NND) C[(size_t)m * 512 + tpos] = f2b(acc[i][j][r] + bb);
      }
    }
  }
}

// ---------------- q/k logits (merged xu+xi passes) ----------------
__global__ void __launch_bounds__(256) k_qk(
    const float* __restrict__ xu, const float* __restrict__ xi,
    const float* __restrict__ FW, const float* __restrict__ FB,
    float* __restrict__ K0, float* __restrict__ Q1, float* __restrict__ Q2,
    float* __restrict__ K2, float* __restrict__ Q0, float* __restrict__ K1) {
  int lane = threadIdx.x & 63, wid = threadIdx.x >> 6;
  if (blockIdx.x < 1024) {
    int stride = 1024 * 4;
    for (int row = blockIdx.x * 4 + wid; row < NND; row += stride) {
      float4 xv = *(const float4*)(xu + (size_t)row * 256 + lane * 4);
      {
        float p[16];
#pragma unroll
        for (int c = 0; c < 16; c++) {
          const float4 wv = *(const float4*)(FW + (size_t)(8 + c) * 256 + lane * 4);
          p[c] = xv.x * wv.x + xv.y * wv.y + xv.z * wv.z + xv.w * wv.w;
        }
#pragma unroll
        for (int off = 1; off < 64; off <<= 1)
#pragma unroll
          for (int c = 0; c < 16; c++) p[c] += __shfl_xor(p[c], off, 64);
        if (lane == 0) {
#pragma unroll
          for (int c = 0; c < 8; c++) K0[row * 8 + c] = p[c] + FB[8 + c];
#pragma unroll
          for (int c = 0; c < 8; c++) Q1[row * 8 + c] = p[8 + c] + FB[16 + c];
        }
      }
      {
        float p[16];
#pragma unroll
        for (int c = 0; c < 16; c++) {
          const float4 wv = *(const float4*)(FW + (size_t)(32 + c) * 256 + lane * 4);
          p[c] = xv.x * wv.x + xv.y * wv.y + xv.z * wv.z + xv.w * wv.w;
        }
#pragma unroll
        for (int off = 1; off < 64; off <<= 1)
#pragma unroll
          for (int c = 0; c < 16; c++) p[c] += __shfl_xor(p[c], off, 64);
        if (lane == 0) {
#pragma unroll
          for (int c = 0; c < 8; c++) Q2[row * 8 + c] = p[c] + FB[32 + c];
#pragma unroll
          for (int c = 0; c < 8; c++) K2[row * 8 + c] = p[8 + c] + FB[40 + c];
        }
      }
    }
  } else {
    int b = blockIdx.x - 1024;
    int stride = 512 * 4;
    for (int row = b * 4 + wid; row < NND; row += stride) {
      float4 xv = *(const float4*)(xi + (size_t)row * 256 + lane * 4);
      float p[16];
#pragma unroll
      for (int c = 0; c < 16; c++) {
        const float4 wv = *(const float4*)(FW + (size_t)((c < 8) ? c : (16 + c)) * 256 + lane * 4);
        p[c] = xv.x * wv.x + xv.y * wv.y + xv.z * wv.z + xv.w * wv.w;
      }
#pragma unroll
      for (int off = 1; off < 64; off <<= 1)
#pragma unroll
        for (int c = 0; c < 16; c++) p[c] += __shfl_xor(p[c], off, 64);
      if (lane == 0) {
#pragma unroll
        for (int c = 0; c < 8; c++) Q0[row * 8 + c] = p[c] + FB[c];
#pragma unroll
        for (int c = 0; c < 8; c++) K1[row * 8 + c] = p[8 + c] + FB[24 + c];
      }
    }
  }
}

// ---------------- edge aggregation: single-pass, 2 waves/dst, 4x-unrolled gather ----------------
__global__ void __launch_bounds__(256) k_edge(
    const int* __restrict__ rp, const int* __restrict__ dg, const u16* __restrict__ csrc,
    const float* __restrict__ q, const float* __restrict__ k,
    const u16* __restrict__ hs, float* __restrict__ out,
    float scale, int accum) {
  __shared__ float exw[4][64 * 8];
  __shared__ int sarr[4][64];
  __shared__ float sd[4][8];
  __shared__ float sacc[4][64];
  int lane = threadIdx.x & 63, w = threadIdx.x >> 6;
  int dst = blockIdx.x * 2 + (w >> 1);
  int half = w & 1;
  int beg = rp[dst];
  int deg = dg[dst];
  int hlen = (deg + 1) >> 1;
  int s0 = half ? hlen : 0;
  int s1 = half ? deg : hlen;
  float qv[8];
  {
    float4 q0 = *(const float4*)(q + dst * 8);
    float4 q1 = *(const float4*)(q + dst * 8 + 4);
    qv[0] = q0.x; qv[1] = q0.y; qv[2] = q0.z; qv[3] = q0.w;
    qv[4] = q1.x; qv[5] = q1.y; qv[6] = q1.z; qv[7] = q1.w;
  }
  float num[8] = {0, 0, 0, 0, 0, 0, 0, 0};
  float dsum[8] = {0, 0, 0, 0, 0, 0, 0, 0};
  for (int base = s0; base < s1; base += 64) {
    int i = base + lane;
    int nn = min(64, s1 - base);
    if (i < s1) {
      int s = (int)csrc[beg + i];
      sarr[w][lane] = s;
      float4 k0 = *(const float4*)(k + s * 8);
      float4 k1 = *(const float4*)(k + s * 8 + 4);
      float kv[8] = {k0.x, k0.y, k0.z, k0.w, k1.x, k1.y, k1.z, k1.w};
#pragma unroll
      for (int h = 0; h < 8; h++) {
        float e = qv[h] + kv[h];
        e = e > 0.f ? e : 0.2f * e;
        float wgt = exp2f(e * 1.44269504f);
        exw[w][lane * 8 + h] = wgt;
        dsum[h] += wgt;
      }
    }
    __asm__ __volatile__("s_waitcnt lgkmcnt(0)" ::: "memory");
    int j = 0;
    for (; j + 4 <= nn; j += 4) {
      int sa = sarr[w][j], sb = sarr[w][j + 1], sc = sarr[w][j + 2], sdn = sarr[w][j + 3];
      uint4 ua = *(const uint4*)(hs + (size_t)sa * 512 + lane * 8);
      uint4 ub = *(const uint4*)(hs + (size_t)sb * 512 + lane * 8);
      uint4 uc = *(const uint4*)(hs + (size_t)sc * 512 + lane * 8);
      uint4 ud = *(const uint4*)(hs + (size_t)sdn * 512 + lane * 8);
      float4 wa0 = *(const float4*)&exw[w][j * 8],       wa1 = *(const float4*)&exw[w][j * 8 + 4];
      float4 wb0 = *(const float4*)&exw[w][j * 8 + 8],   wb1 = *(const float4*)&exw[w][j * 8 + 12];
      float4 wc0 = *(const float4*)&exw[w][j * 8 + 16],  wc1 = *(const float4*)&exw[w][j * 8 + 20];
      float4 wd0 = *(const float4*)&exw[w][j * 8 + 24],  wd1 = *(const float4*)&exw[w][j * 8 + 28];
      accum8(num, ua, wa0, wa1);
      accum8(num, ub, wb0, wb1);
      accum8(num, uc, wc0, wc1);
      accum8(num, ud, wd0, wd1);
    }
    for (; j < nn; j++) {
      int s = sarr[w][j];
      uint4 u = *(const uint4*)(hs + (size_t)s * 512 + lane * 8);
      float4 e0 = *(const float4*)&exw[w][j * 8];
      float4 e1 = *(const float4*)&exw[w][j * 8 + 4];
      accum8(num, u, e0, e1);
    }
  }
#pragma unroll
  for (int off = 1; off < 64; off <<= 1)
#pragma unroll
    for (int h = 0; h < 8; h++) dsum[h] += __shfl_xor(dsum[h], off, 64);
  if (lane == 0) {
#pragma unroll
    for (int h = 0; h < 8; h++) sd[w][h] = dsum[h];
  }
  __syncthreads();
  float acc = 0.f;
#pragma unroll
  for (int h = 0; h < 8; h++) {
    float tot = sd[w][h] + sd[w ^ 1][h];
    float rden = tot > 0.f ? 1.f / tot : 0.f;
    acc += num[h] * rden;
  }
  acc *= scale;
  sacc[w][lane] = acc;
  __syncthreads();
  if (half == 0) {
    float tot = sacc[w][lane] + sacc[w + 1][lane];
    if (accum) out[dst * 64 + lane] += tot;
    else out[dst * 64 + lane] = tot;
  }
}

extern "C" void kernel_launch(void* const* d_in, const int* in_sizes, int n_in,
                              void* d_out, int out_size, void* d_ws, size_t ws_size,
                              hipStream_t stream) {
  const float* xu = (const float*)d_in[0];
  const float* xi = (const float*)d_in[1];
  const float* Wv = (const float*)d_in[2];
  const float* bv = (const float*)d_in[3];
  const float* Wq = (const float*)d_in[4];
  const float* bq = (const float*)d_in[5];
  const float* Wk = (const float*)d_in[6];
  const float* bk = (const float*)d_in[7];
  const int* src1 = (const int*)d_in[8];
  const int* dst1 = (const int*)d_in[9];
  const int* src2 = (const int*)d_in[10];
  const int* dst2 = (const int*)d_in[11];
  const int* src3 = (const int*)d_in[12];
  const int* dst3 = (const int*)d_in[13];
  float* out_user = (float*)d_out;
  float* out_item = out_user + (size_t)NND * 64;

  char* w = (char*)d_ws;
  auto alloc = [&](size_t sz) -> char* {
    char* p = w; w += (sz + 255) & ~(size_t)255; return p;
  };
  // total ~77 MB (round-12 proven layout)
  u16* H     = (u16*)alloc((size_t)NND * 512 * 2);          // 51.2 MB shared h table
  u16* WT    = (u16*)alloc((size_t)3 * 512 * 256 * 2);      // 0.8 MB
  float* WVT = (float*)alloc((size_t)3 * 512 * 256 * 4);    // 1.6 MB fp32 transpose
  float* FW  = (float*)alloc((size_t)3 * 16 * 256 * 4);     // fused qk weights
  float* FB  = (float*)alloc((size_t)3 * 16 * 4);
  float* Q0 = (float*)alloc((size_t)NND * 8 * 4);
  float* K0 = (float*)alloc((size_t)NND * 8 * 4);
  float* Q1 = (float*)alloc((size_t)NND * 8 * 4);
  float* K1 = (float*)alloc((size_t)NND * 8 * 4);
  float* Q2 = (float*)alloc((size_t)NND * 8 * 4);
  float* K2 = (float*)alloc((size_t)NND * 8 * 4);
  int* ROWPTR = (int*)alloc((size_t)3 * NND * 4);
  int* DEG    = (int*)alloc((size_t)3 * NND * 4);
  int* BCUR   = (int*)alloc(TOTB * 4);
  u16* CSRC   = (u16*)alloc((size_t)TOTB * CAPB * 2);      // 12.0 MB padded u16
  unsigned* PAIRS = (unsigned*)H;                          // aliased (24 MB < 51.2 MB); dead before H written
  (void)ws_size; (void)n_in; (void)in_sizes; (void)out_size;

  // --- weight prep (+ bucket cursor init) ---
  k_prepw<<<(3 * 512 * 256 + 255) / 256, 256, 0, stream>>>(Wv, WT, WVT, BCUR);

  // --- CSR build (fixed-capacity buckets: scatter + group only) ---
  kb_scatter<<<dim3((EDG + TS - 1) / TS, 3), 256, 0, stream>>>(src1, dst1, src2, dst2, src3, dst3, BCUR, PAIRS);
  kb_build<<<dim3(NBK, 3), 256, 0, stream>>>(PAIRS, BCUR, ROWPTR, DEG, CSRC);

  // --- fused q/k weights + logits ---
  k_fusew2<<<48, 256, 0, stream>>>(WVT, bv, Wq, bq, Wk, bk, FW, FB);
  k_qk<<<1536, 256, 0, stream>>>(xu, xi, FW, FB, K0, Q1, Q2, K2, Q0, K1);

  // --- per relation: GEMM into shared H, then edge aggregation ---
  dim3 gg(4, NBK);   // N fast, M slow: A row-block shared across adjacent blocks
  k_gemm<<<gg, 256, 0, stream>>>(xu, WT, bv, H);
  k_edge<<<NND / 2, 256, 0, stream>>>(ROWPTR, DEG, CSRC, Q0, K0, H, out_item, 0.125f, 0);
  k_gemm<<<gg, 256, 0, stream>>>(xi, WT + 512 * 256, bv + 512, H);
  k_edge<<<NND / 2, 256, 0, stream>>>(ROWPTR + NND, DEG + NND, CSRC, Q1, K1, H, out_user, 0.0625f, 0);
  k_gemm<<<gg, 256, 0, stream>>>(xu, WT + 2 * 512 * 256, bv + 1024, H);
  k_edge<<<NND / 2, 256, 0, stream>>>(ROWPTR + 2 * NND, DEG + 2 * NND, CSRC, Q2, K2, H, out_user, 0.0625f, 1);
}